// Round 18
// baseline (805.475 us; speedup 1.0000x reference)
//
#include <hip/hip_runtime.h>
#include <math.h>

#define BTOT   32768
#define NNODE  78
#define NEMB   30
#define NPROJ  10
#define NGR    7
#define ROW    (NNODE*NEMB)       // 2340 floats per batch
#define BPW    8                  // batches per WG (8 half-waves, 256 thr)
#define FEAT_OUT (BTOT*NGR*NEMB)
#define NWG    (BTOT/BPW)         // 4096
#define NSLOT  64                 // atomic contention spread (R7-proven)
#define SLOTP  80                 // padded stride per slot (floats)

__constant__ int d_off[NGR] = {0,5,14,23,48,57,66};
__constant__ int d_len[NGR] = {5,9,9,25,9,9,12};

// ---- cross-lane allreduce: 4 DPP steps (VALU) + ds_swizzle xor16 ----
template<int CTRL>
__device__ __forceinline__ float dpp_f(float x) {
  return __int_as_float(__builtin_amdgcn_update_dpp(0, __float_as_int(x), CTRL, 0xF, 0xF, true));
}
__device__ __forceinline__ float swz16(float x) {
  return __int_as_float(__builtin_amdgcn_ds_swizzle(__float_as_int(x), 0x401F));
}
__device__ __forceinline__ float hsum32(float x) {
  x += dpp_f<0xB1>(x);    // quad_perm xor1
  x += dpp_f<0x4E>(x);    // quad_perm xor2
  x += dpp_f<0x141>(x);   // row_half_mirror
  x += dpp_f<0x140>(x);   // row_mirror
  x += swz16(x);          // xor16
  return x;
}

// ---- R12-validated pieces: load burst / compute body ----
template<int LEN>
__device__ __forceinline__ void load_rows(const float* __restrict__ xsub,
                                          float (&xr)[LEN], int e) {
#pragma unroll
  for (int j = 0; j < LEN; ++j) xr[j] = xsub[j * NEMB + e];  // 120B/row
}

template<int OFF, int LEN, int G>
__device__ __forceinline__ void compute_graph(
    const float (&xr)[LEN], const float (&Wr)[NPROJ],
    float* __restrict__ arow, float* __restrict__ outb,
    int lane31, bool evalid, int e)
{
  float xsum = 0.f;
#pragma unroll
  for (int j = 0; j < LEN; ++j) xsum += xr[j];
  float t[NPROJ];
#pragma unroll
  for (int h = 0; h < NPROJ; ++h) t[h] = hsum32(Wr[h] * xsum);
  float u = 0.f;
#pragma unroll
  for (int h = 0; h < NPROJ; ++h) u = fmaf(Wr[h], t[h], u);
  float lg[LEN];
#pragma unroll
  for (int j = 0; j < LEN; ++j) lg[j] = hsum32(xr[j] * u);
  float m = lg[0];
#pragma unroll
  for (int j = 1; j < LEN; ++j) m = fmaxf(m, lg[j]);
  float s = 0.f;
#pragma unroll
  for (int j = 0; j < LEN; ++j) { lg[j] = __expf(lg[j] - m); s += lg[j]; }
  float inv = 1.f / s;
  float f = 0.f, myatt = 0.f;
#pragma unroll
  for (int j = 0; j < LEN; ++j) {
    float a = lg[j] * inv;
    f = fmaf(a, xr[j], f);
    if (lane31 == j) myatt = a;
  }
  if (evalid) outb[G * NEMB + e] = f;            // 120B contiguous store
  if (lane31 < LEN) arow[OFF + lane31] = myatt;
}

__global__ __launch_bounds__(256) void meso_main(
    const float* __restrict__ x, const float* __restrict__ wt,
    float* __restrict__ out, float* __restrict__ attpart,
    unsigned* __restrict__ counter, const float* __restrict__ coords)
{
  __shared__ float att_all[BPW][NNODE];   // 2.4 KB

  const int tid    = threadIdx.x;
  const int half   = tid >> 5;
  const int lane31 = tid & 31;
  const bool evalid = lane31 < NEMB;
  const int e = evalid ? lane31 : (NEMB - 1);

  float Wr[NPROJ];
#pragma unroll
  for (int h = 0; h < NPROJ; ++h) Wr[h] = evalid ? wt[e * NPROJ + h] : 0.f;

  const long long b = (long long)blockIdx.x * BPW + half;
  const float* xrow = x + b * ROW;
  float* outb = out + b * (NGR * NEMB);
  float* arow = att_all[half];

  // ---- software pipeline (R12 measured-best) ----
  float xr0[5], xr1[9], xr2[9], xr3[25], xr4[9], xr5[9], xr6[12];
  load_rows< 5>(xrow +  0*NEMB, xr0, e);
  load_rows< 9>(xrow +  5*NEMB, xr1, e);
  compute_graph< 0, 5,0>(xr0, Wr, arow, outb, lane31, evalid, e);
  load_rows< 9>(xrow + 14*NEMB, xr2, e);
  compute_graph< 5, 9,1>(xr1, Wr, arow, outb, lane31, evalid, e);
  load_rows<25>(xrow + 23*NEMB, xr3, e);
  compute_graph<14, 9,2>(xr2, Wr, arow, outb, lane31, evalid, e);
  load_rows< 9>(xrow + 48*NEMB, xr4, e);
  compute_graph<23,25,3>(xr3, Wr, arow, outb, lane31, evalid, e);
  load_rows< 9>(xrow + 57*NEMB, xr5, e);
  compute_graph<48, 9,4>(xr4, Wr, arow, outb, lane31, evalid, e);
  load_rows<12>(xrow + 66*NEMB, xr6, e);
  compute_graph<57, 9,5>(xr5, Wr, arow, outb, lane31, evalid, e);
  compute_graph<66,12,6>(xr6, Wr, arow, outb, lane31, evalid, e);

  __syncthreads();
  // 64-way contention spread (R7-proven)
  if (tid < NNODE) {
    float s = 0.f;
#pragma unroll
    for (int h = 0; h < BPW; ++h) s += att_all[h][tid];
    atomicAdd(&attpart[(blockIdx.x & (NSLOT-1)) * SLOTP + tid], s);
  }

  // ---- fused coordinate epilogue: last WG reduces attpart and writes 21 floats ----
  __shared__ unsigned lastflag;
  __shared__ float asum[NNODE];
  __threadfence();                       // release our attpart adds before ticket
  if (tid == 0)
    lastflag = (atomicAdd(counter, 1u) == (unsigned)(NWG - 1)) ? 1u : 0u;
  __syncthreads();
  if (lastflag) {
    // all other WGs' fences precede their ticket -> their adds are visible.
    // agent-scope loads avoid stale per-XCD/L1 lines.
    if (tid < NNODE) {
      float s = 0.f;
#pragma unroll
      for (int k = 0; k < NSLOT; ++k)
        s += __hip_atomic_load(&attpart[k * SLOTP + tid],
                               __ATOMIC_RELAXED, __HIP_MEMORY_SCOPE_AGENT);
      asum[tid] = s;
    }
    __syncthreads();
    if (tid < NGR*3) {
      int g = tid / 3, kk = tid % 3;
      int off = d_off[g], len = d_len[g];
      float s = 0.f;
      for (int j = 0; j < len; ++j) s += asum[off+j] * coords[(off+j)*3 + kk];
      out[FEAT_OUT + tid] = s * (1.0f/(float)BTOT);
    }
  }
}

extern "C" void kernel_launch(void* const* d_in, const int* in_sizes, int n_in,
                              void* d_out, int out_size, void* d_ws, size_t ws_size,
                              hipStream_t stream) {
  const float* x      = (const float*)d_in[0];
  const float* coords = (const float*)d_in[1];
  const float* wt     = (const float*)d_in[2];
  float* out      = (float*)d_out;
  float* attpart  = (float*)d_ws;                          // 64*80 floats
  unsigned* counter = (unsigned*)((char*)d_ws + NSLOT*SLOTP*sizeof(float));

  // zero attpart slots + ticket counter (20.5 KB) each launch — deterministic
  hipMemsetAsync(d_ws, 0, NSLOT*SLOTP*sizeof(float) + sizeof(unsigned), stream);
  meso_main<<<NWG, 256, 0, stream>>>(x, wt, out, attpart, counter, coords);
}

// Round 19
// 80.958 us; speedup vs baseline: 9.9494x; 9.9494x over previous
//
#include <hip/hip_runtime.h>
#include <math.h>

#define BTOT   32768
#define NNODE  78
#define NEMB   30
#define NPROJ  10
#define NGR    7
#define ROW    (NNODE*NEMB)       // 2340 floats per batch
#define BPW    8                  // batches per WG (8 half-waves, 256 thr)
#define FEAT_OUT (BTOT*NGR*NEMB)
#define NSLOT  64                 // atomic contention spread
#define SLOTP  80                 // padded stride per slot (floats)

__constant__ int d_off[NGR] = {0,5,14,23,48,57,66};
__constant__ int d_len[NGR] = {5,9,9,25,9,9,12};

// ---- cross-lane allreduce: 4 DPP steps (VALU) + ds_swizzle xor16 ----
template<int CTRL>
__device__ __forceinline__ float dpp_f(float x) {
  return __int_as_float(__builtin_amdgcn_update_dpp(0, __float_as_int(x), CTRL, 0xF, 0xF, true));
}
__device__ __forceinline__ float swz16(float x) {
  return __int_as_float(__builtin_amdgcn_ds_swizzle(__float_as_int(x), 0x401F));
}
__device__ __forceinline__ float hsum32(float x) {
  x += dpp_f<0xB1>(x);    // quad_perm xor1
  x += dpp_f<0x4E>(x);    // quad_perm xor2
  x += dpp_f<0x141>(x);   // row_half_mirror
  x += dpp_f<0x140>(x);   // row_mirror
  x += swz16(x);          // xor16
  return x;
}

// ---- pipelined pieces: load burst (independent, issued early) / compute body ----
template<int LEN>
__device__ __forceinline__ void load_rows(const float* __restrict__ xsub,
                                          float (&xr)[LEN], int e) {
#pragma unroll
  for (int j = 0; j < LEN; ++j) xr[j] = xsub[j * NEMB + e];  // 120B/row, contiguous
}

template<int OFF, int LEN, int G>
__device__ __forceinline__ void compute_graph(
    const float (&xr)[LEN], const float (&Wr)[NPROJ],
    float* __restrict__ arow, float* __restrict__ outb,
    int lane31, bool evalid, int e)
{
  float xsum = 0.f;
#pragma unroll
  for (int j = 0; j < LEN; ++j) xsum += xr[j];
  // t[h] = sum_e W[e,h]*xsum[e]  (Wr=0 in lanes 30,31 neutralizes clamp garbage)
  float t[NPROJ];
#pragma unroll
  for (int h = 0; h < NPROJ; ++h) t[h] = hsum32(Wr[h] * xsum);
  // u[e] = sum_h W[e,h] t[h]
  float u = 0.f;
#pragma unroll
  for (int h = 0; h < NPROJ; ++h) u = fmaf(Wr[h], t[h], u);
  // logits: allreduce -> every lane holds every logit
  float lg[LEN];
#pragma unroll
  for (int j = 0; j < LEN; ++j) lg[j] = hsum32(xr[j] * u);
  // softmax per-lane (uniform across lanes)
  float m = lg[0];
#pragma unroll
  for (int j = 1; j < LEN; ++j) m = fmaxf(m, lg[j]);
  float s = 0.f;
#pragma unroll
  for (int j = 0; j < LEN; ++j) { lg[j] = __expf(lg[j] - m); s += lg[j]; }
  float inv = 1.f / s;
  // feat + park own att
  float f = 0.f, myatt = 0.f;
#pragma unroll
  for (int j = 0; j < LEN; ++j) {
    float a = lg[j] * inv;
    f = fmaf(a, xr[j], f);
    if (lane31 == j) myatt = a;
  }
  if (evalid) outb[G * NEMB + e] = f;            // 120B contiguous store
  if (lane31 < LEN) arow[OFF + lane31] = myatt;
}

__global__ __launch_bounds__(256) void meso_main(
    const float* __restrict__ x, const float* __restrict__ wt,
    float* __restrict__ out, float* __restrict__ attpart)
{
  __shared__ float att_all[BPW][NNODE];   // 2.4 KB

  const int tid    = threadIdx.x;
  const int half   = tid >> 5;
  const int lane31 = tid & 31;
  const bool evalid = lane31 < NEMB;
  const int e = evalid ? lane31 : (NEMB - 1);

  float Wr[NPROJ];
#pragma unroll
  for (int h = 0; h < NPROJ; ++h) Wr[h] = evalid ? wt[e * NPROJ + h] : 0.f;

  const long long b = (long long)blockIdx.x * BPW + half;
  const float* xrow = x + b * ROW;
  float* outb = out + b * (NGR * NEMB);
  float* arow = att_all[half];

  // ---- software pipeline: issue graph g+1's loads before computing graph g ----
  float xr0[5], xr1[9], xr2[9], xr3[25], xr4[9], xr5[9], xr6[12];
  load_rows< 5>(xrow +  0*NEMB, xr0, e);
  load_rows< 9>(xrow +  5*NEMB, xr1, e);
  compute_graph< 0, 5,0>(xr0, Wr, arow, outb, lane31, evalid, e);
  load_rows< 9>(xrow + 14*NEMB, xr2, e);
  compute_graph< 5, 9,1>(xr1, Wr, arow, outb, lane31, evalid, e);
  load_rows<25>(xrow + 23*NEMB, xr3, e);
  compute_graph<14, 9,2>(xr2, Wr, arow, outb, lane31, evalid, e);
  load_rows< 9>(xrow + 48*NEMB, xr4, e);
  compute_graph<23,25,3>(xr3, Wr, arow, outb, lane31, evalid, e);
  load_rows< 9>(xrow + 57*NEMB, xr5, e);
  compute_graph<48, 9,4>(xr4, Wr, arow, outb, lane31, evalid, e);
  load_rows<12>(xrow + 66*NEMB, xr6, e);
  compute_graph<57, 9,5>(xr5, Wr, arow, outb, lane31, evalid, e);
  compute_graph<66,12,6>(xr6, Wr, arow, outb, lane31, evalid, e);

  __syncthreads();
  // 64-way contention spread: WG w accumulates into slot (w & 63)
  if (tid < NNODE) {
    float s = 0.f;
#pragma unroll
    for (int h = 0; h < BPW; ++h) s += att_all[h][tid];
    atomicAdd(&attpart[(blockIdx.x & (NSLOT-1)) * SLOTP + tid], s);
  }
}

__global__ __launch_bounds__(128) void meso_coor(
    const float* __restrict__ attpart,
    const float* __restrict__ coords,
    float* __restrict__ out_coor)
{
  __shared__ float asum[NNODE];
  int t = threadIdx.x;
  if (t < NNODE) {
    float s = 0.f;
#pragma unroll
    for (int k = 0; k < NSLOT; ++k) s += attpart[k * SLOTP + t];
    asum[t] = s;
  }
  __syncthreads();
  if (t < NGR*3) {
    int g = t / 3, kk = t % 3;
    int off = d_off[g], len = d_len[g];
    float s = 0.f;
    for (int j = 0; j < len; ++j) s += asum[off+j] * coords[(off+j)*3 + kk];
    out_coor[t] = s * (1.0f/(float)BTOT);
  }
}

extern "C" void kernel_launch(void* const* d_in, const int* in_sizes, int n_in,
                              void* d_out, int out_size, void* d_ws, size_t ws_size,
                              hipStream_t stream) {
  const float* x      = (const float*)d_in[0];
  const float* coords = (const float*)d_in[1];
  const float* wt     = (const float*)d_in[2];
  float* out     = (float*)d_out;
  float* attpart = (float*)d_ws;

  hipMemsetAsync(attpart, 0, NSLOT * SLOTP * sizeof(float), stream);
  meso_main<<<BTOT/BPW, 256, 0, stream>>>(x, wt, out, attpart);
  meso_coor<<<1, 128, 0, stream>>>(attpart, coords, out + FEAT_OUT);
}

// Round 20
// 80.487 us; speedup vs baseline: 10.0075x; 1.0058x over previous
//
#include <hip/hip_runtime.h>
#include <math.h>

#define BTOT   32768
#define NNODE  78
#define NEMB   30
#define NPROJ  10
#define NGR    7
#define ROW    (NNODE*NEMB)       // 2340 floats per batch
#define BPW    8                  // batches per WG (8 half-waves, 256 thr)
#define FEAT_OUT (BTOT*NGR*NEMB)
#define NSLOT  64                 // atomic contention spread
#define SLOTP  80                 // padded stride per slot (floats)

__constant__ int d_off[NGR] = {0,5,14,23,48,57,66};
__constant__ int d_len[NGR] = {5,9,9,25,9,9,12};

// ---- cross-lane allreduce: 4 DPP steps (VALU) + ds_swizzle xor16 ----
template<int CTRL>
__device__ __forceinline__ float dpp_f(float x) {
  return __int_as_float(__builtin_amdgcn_update_dpp(0, __float_as_int(x), CTRL, 0xF, 0xF, true));
}
__device__ __forceinline__ float swz16(float x) {
  return __int_as_float(__builtin_amdgcn_ds_swizzle(__float_as_int(x), 0x401F));
}
__device__ __forceinline__ float hsum32(float x) {
  x += dpp_f<0xB1>(x);    // quad_perm xor1
  x += dpp_f<0x4E>(x);    // quad_perm xor2
  x += dpp_f<0x141>(x);   // row_half_mirror
  x += dpp_f<0x140>(x);   // row_mirror
  x += swz16(x);          // xor16
  return x;
}

// ---- pipelined pieces: load burst (independent, issued early) / compute body ----
template<int LEN>
__device__ __forceinline__ void load_rows(const float* __restrict__ xsub,
                                          float (&xr)[LEN], int e) {
#pragma unroll
  for (int j = 0; j < LEN; ++j) xr[j] = xsub[j * NEMB + e];  // 120B/row, contiguous
}

template<int OFF, int LEN, int G>
__device__ __forceinline__ void compute_graph(
    const float (&xr)[LEN], const float (&Wr)[NPROJ],
    float* __restrict__ arow, float* __restrict__ outb,
    int lane31, bool evalid, int e)
{
  float xsum = 0.f;
#pragma unroll
  for (int j = 0; j < LEN; ++j) xsum += xr[j];
  // t[h] = sum_e W[e,h]*xsum[e]  (Wr=0 in lanes 30,31 neutralizes clamp garbage)
  float t[NPROJ];
#pragma unroll
  for (int h = 0; h < NPROJ; ++h) t[h] = hsum32(Wr[h] * xsum);
  // u[e] = sum_h W[e,h] t[h]
  float u = 0.f;
#pragma unroll
  for (int h = 0; h < NPROJ; ++h) u = fmaf(Wr[h], t[h], u);
  // logits: allreduce -> every lane holds every logit
  float lg[LEN];
#pragma unroll
  for (int j = 0; j < LEN; ++j) lg[j] = hsum32(xr[j] * u);
  // softmax per-lane (uniform across lanes)
  float m = lg[0];
#pragma unroll
  for (int j = 1; j < LEN; ++j) m = fmaxf(m, lg[j]);
  float s = 0.f;
#pragma unroll
  for (int j = 0; j < LEN; ++j) { lg[j] = __expf(lg[j] - m); s += lg[j]; }
  float inv = 1.f / s;
  // feat + park own att
  float f = 0.f, myatt = 0.f;
#pragma unroll
  for (int j = 0; j < LEN; ++j) {
    float a = lg[j] * inv;
    f = fmaf(a, xr[j], f);
    if (lane31 == j) myatt = a;
  }
  if (evalid) outb[G * NEMB + e] = f;            // 120B contiguous store
  if (lane31 < LEN) arow[OFF + lane31] = myatt;
}

__global__ __launch_bounds__(256) void meso_main(
    const float* __restrict__ x, const float* __restrict__ wt,
    float* __restrict__ out, float* __restrict__ attpart)
{
  __shared__ float att_all[BPW][NNODE];   // 2.4 KB

  const int tid    = threadIdx.x;
  const int half   = tid >> 5;
  const int lane31 = tid & 31;
  const bool evalid = lane31 < NEMB;
  const int e = evalid ? lane31 : (NEMB - 1);

  float Wr[NPROJ];
#pragma unroll
  for (int h = 0; h < NPROJ; ++h) Wr[h] = evalid ? wt[e * NPROJ + h] : 0.f;

  const long long b = (long long)blockIdx.x * BPW + half;
  const float* xrow = x + b * ROW;
  float* outb = out + b * (NGR * NEMB);
  float* arow = att_all[half];

  // ---- 2-deep software pipeline: loads for g+1 AND g+2 in flight during g ----
  float xr0[5], xr1[9], xr2[9], xr3[25], xr4[9], xr5[9], xr6[12];
  load_rows< 5>(xrow +  0*NEMB, xr0, e);
  load_rows< 9>(xrow +  5*NEMB, xr1, e);
  load_rows< 9>(xrow + 14*NEMB, xr2, e);
  compute_graph< 0, 5,0>(xr0, Wr, arow, outb, lane31, evalid, e);
  load_rows<25>(xrow + 23*NEMB, xr3, e);
  compute_graph< 5, 9,1>(xr1, Wr, arow, outb, lane31, evalid, e);
  load_rows< 9>(xrow + 48*NEMB, xr4, e);
  compute_graph<14, 9,2>(xr2, Wr, arow, outb, lane31, evalid, e);
  load_rows< 9>(xrow + 57*NEMB, xr5, e);
  compute_graph<23,25,3>(xr3, Wr, arow, outb, lane31, evalid, e);
  load_rows<12>(xrow + 66*NEMB, xr6, e);
  compute_graph<48, 9,4>(xr4, Wr, arow, outb, lane31, evalid, e);
  compute_graph<57, 9,5>(xr5, Wr, arow, outb, lane31, evalid, e);
  compute_graph<66,12,6>(xr6, Wr, arow, outb, lane31, evalid, e);

  __syncthreads();
  // 64-way contention spread: WG w accumulates into slot (w & 63)
  if (tid < NNODE) {
    float s = 0.f;
#pragma unroll
    for (int h = 0; h < BPW; ++h) s += att_all[h][tid];
    atomicAdd(&attpart[(blockIdx.x & (NSLOT-1)) * SLOTP + tid], s);
  }
}

__global__ __launch_bounds__(128) void meso_coor(
    const float* __restrict__ attpart,
    const float* __restrict__ coords,
    float* __restrict__ out_coor)
{
  __shared__ float asum[NNODE];
  int t = threadIdx.x;
  if (t < NNODE) {
    float s = 0.f;
#pragma unroll
    for (int k = 0; k < NSLOT; ++k) s += attpart[k * SLOTP + t];
    asum[t] = s;
  }
  __syncthreads();
  if (t < NGR*3) {
    int g = t / 3, kk = t % 3;
    int off = d_off[g], len = d_len[g];
    float s = 0.f;
    for (int j = 0; j < len; ++j) s += asum[off+j] * coords[(off+j)*3 + kk];
    out_coor[t] = s * (1.0f/(float)BTOT);
  }
}

extern "C" void kernel_launch(void* const* d_in, const int* in_sizes, int n_in,
                              void* d_out, int out_size, void* d_ws, size_t ws_size,
                              hipStream_t stream) {
  const float* x      = (const float*)d_in[0];
  const float* coords = (const float*)d_in[1];
  const float* wt     = (const float*)d_in[2];
  float* out     = (float*)d_out;
  float* attpart = (float*)d_ws;

  hipMemsetAsync(attpart, 0, NSLOT * SLOTP * sizeof(float), stream);
  meso_main<<<BTOT/BPW, 256, 0, stream>>>(x, wt, out, attpart);
  meso_coor<<<1, 128, 0, stream>>>(attpart, coords, out + FEAT_OUT);
}